// Round 10
// baseline (165.049 us; speedup 1.0000x reference)
//
#include <hip/hip_runtime.h>

#define D 64
#define D4 (D / 4)         // 16 float4 per fp32 row
#define SBSHIFT 9          // 512 nodes per super-bucket
#define SBROWS 512
#define HALF 256           // each sb_gather block handles one 256-node half
#define CHUNK_E 8192       // edges per chunk_sort block
#define STAGE_CAP 4608     // sb_gather staging (mean ~4092 per half, +8 sigma)
#define NCH_MAX 256
#define NSB_MAX 256

typedef float f32x4 __attribute__((ext_vector_type(4)));

__device__ __forceinline__ float elu1(float z) {
    return z > 0.0f ? z : expm1f(z);
}

// pack two fp32 -> bf16 pair (RNE), a in low 16, b in high 16
__device__ __forceinline__ unsigned int bfpair(float a, float b) {
    unsigned int ua = __float_as_uint(a);
    unsigned int ub = __float_as_uint(b);
    ua = (ua + 0x7FFFu + ((ua >> 16) & 1u)) >> 16;
    ub = (ub + 0x7FFFu + ((ub >> 16) & 1u)) & 0xFFFF0000u;
    return ub | ua;
}

// ---------- K1: emb16 = bf16(elu(x*w)); 32B/lane read, 16B/lane write ----------
__global__ void emb_kernel(const float* __restrict__ x,
                           const float* __restrict__ w,
                           uint4* __restrict__ emb16,
                           int total8) {
    int i = blockIdx.x * blockDim.x + threadIdx.x;
    if (i >= total8) return;
    f32x4 a = __builtin_nontemporal_load((const f32x4*)x + 2 * i);
    f32x4 b = __builtin_nontemporal_load((const f32x4*)x + 2 * i + 1);
    float4 wa = ((const float4*)w)[(2 * i) & 15];
    float4 wb = ((const float4*)w)[(2 * i + 1) & 15];
    uint4 o;
    o.x = bfpair(elu1(a.x * wa.x), elu1(a.y * wa.y));
    o.y = bfpair(elu1(a.z * wa.z), elu1(a.w * wa.w));
    o.z = bfpair(elu1(b.x * wb.x), elu1(b.y * wb.y));
    o.w = bfpair(elu1(b.z * wb.z), elu1(b.w * wb.w));
    emb16[i] = o;
}

// ---------- K2: per-chunk LDS bucket sort -> LINEAR coalesced flush + cbase ----
__global__ __launch_bounds__(512) void chunk_sort_kernel(
        const int* __restrict__ src, const int* __restrict__ dst,
        int* __restrict__ slots_lin,    // [NCH*CHUNK_E], pad-free
        int* __restrict__ cbase,        // [NCH][257] local run offsets
        int n_edges) {
    __shared__ int hist[256], base[256], cur[256];
    __shared__ int wsum[4];
    __shared__ int stage[CHUNK_E];      // 32 KB
    const int tid = threadIdx.x;
    const int lane = tid & 63, wid = tid >> 6;
    const int c0  = blockIdx.x * CHUNK_E;
    const int kn  = min(CHUNK_E, n_edges - c0);
    const int kn4 = kn >> 2;
    const int tail = kn & 3;

    if (tid < 256) hist[tid] = 0;
    __syncthreads();
    const int4* dst4 = (const int4*)(dst + c0);
    for (int k = tid; k < kn4; k += 512) {
        int4 dv = dst4[k];
        atomicAdd(&hist[dv.x >> SBSHIFT], 1);
        atomicAdd(&hist[dv.y >> SBSHIFT], 1);
        atomicAdd(&hist[dv.z >> SBSHIFT], 1);
        atomicAdd(&hist[dv.w >> SBSHIFT], 1);
    }
    if (tid < tail)
        atomicAdd(&hist[dst[c0 + (kn4 << 2) + tid] >> SBSHIFT], 1);
    __syncthreads();
    int h = 0, incl = 0;
    if (tid < 256) {
        h = hist[tid];
        incl = h;
        #pragma unroll
        for (int off = 1; off < 64; off <<= 1) {
            int t = __shfl_up(incl, off, 64);
            if (lane >= off) incl += t;
        }
        if (lane == 63) wsum[wid] = incl;
    }
    __syncthreads();
    if (tid < 256) {
        int pre = 0;
        for (int k = 0; k < wid; k++) pre += wsum[k];
        int e = pre + incl - h;
        base[tid] = e;
        cur[tid]  = e;
    }
    __syncthreads();
    const int4* src4 = (const int4*)(src + c0);
    for (int k = tid; k < kn4; k += 512) {
        int4 dv = dst4[k];
        int4 sv = src4[k];
        int pos;
        pos = atomicAdd(&cur[dv.x >> SBSHIFT], 1);
        stage[pos] = ((dv.x & (SBROWS - 1)) << 17) | sv.x;
        pos = atomicAdd(&cur[dv.y >> SBSHIFT], 1);
        stage[pos] = ((dv.y & (SBROWS - 1)) << 17) | sv.y;
        pos = atomicAdd(&cur[dv.z >> SBSHIFT], 1);
        stage[pos] = ((dv.z & (SBROWS - 1)) << 17) | sv.z;
        pos = atomicAdd(&cur[dv.w >> SBSHIFT], 1);
        stage[pos] = ((dv.w & (SBROWS - 1)) << 17) | sv.w;
    }
    if (tid < tail) {
        int k = (kn4 << 2) + tid;
        int d = dst[c0 + k], s = src[c0 + k];
        int pos = atomicAdd(&cur[d >> SBSHIFT], 1);
        stage[pos] = ((d & (SBROWS - 1)) << 17) | s;
    }
    __syncthreads();
    for (int j = tid; j < kn; j += 512)
        slots_lin[c0 + j] = stage[j];
    if (tid < 256) cbase[blockIdx.x * 257 + tid] = base[tid];
    if (tid == 0)  cbase[blockIdx.x * 257 + 256] = kn;
}

// ---------- K3: merged fine-sort + gather; block = (sb, node-half) -----------
// Block-local LDS counting sort of its half's edges, then register-accum
// gather straight from LDS order. No global edge positions needed anywhere.
__global__ __launch_bounds__(512) void sb_gather_kernel(
        const unsigned int* __restrict__ emb16,
        const int* __restrict__ slots_lin,
        const int* __restrict__ cbase,
        float* __restrict__ out, int n_nodes, int NCH) {
    __shared__ int rstart[NCH_MAX], rc[NCH_MAX];
    __shared__ int counts[HALF], cur[HALF];
    __shared__ int wsum[4];
    __shared__ int stage[STAGE_CAP];       // 18.4 KB
    const int sb   = blockIdx.x >> 1;
    const int half = blockIdx.x & 1;
    const int tid  = threadIdx.x;          // 512
    const int wid = tid >> 6, lane = tid & 63;
    const int rbase = half << 8;           // dlocal offset of our half
    const int lo = (sb << SBSHIFT) + rbase;
    const int rows_here = min(HALF, n_nodes - lo);
    if (rows_here <= 0) return;            // uniform: whole block exits

    if (tid < NCH) {
        int a = cbase[tid * 257 + sb];
        int b = cbase[tid * 257 + sb + 1];
        rstart[tid] = tid * CHUNK_E + a;
        rc[tid] = b - a;
    }
    if (tid < HALF) counts[tid] = 0;
    __syncthreads();
    // phase 1: histogram of our half's local nodes
    for (int c = wid; c < NCH; c += 8) {
        int n = rc[c], st = rstart[c];
        for (int j = lane; j < n; j += 64) {
            int r = (int)(((unsigned)slots_lin[st + j]) >> 17) - rbase;
            if ((unsigned)r < HALF) atomicAdd(&counts[r], 1);
        }
    }
    __syncthreads();
    // phase 2: exclusive scan of counts[256] on waves 0..3
    int v = 0, incl = 0;
    if (tid < HALF) {
        v = counts[tid];
        incl = v;
        #pragma unroll
        for (int off = 1; off < 64; off <<= 1) {
            int t = __shfl_up(incl, off, 64);
            if (lane >= off) incl += t;
        }
        if (lane == 63) wsum[wid] = incl;
    }
    __syncthreads();
    const int T = wsum[0] + wsum[1] + wsum[2] + wsum[3];
    if (tid < HALF) {
        int pre = 0;
        for (int k = 0; k < wid; k++) pre += wsum[k];
        cur[tid] = pre + incl - v;
    }
    __syncthreads();
    if (T <= STAGE_CAP) {
        // phase 3: scatter our half into LDS stage (block-local positions)
        for (int c = wid; c < NCH; c += 8) {
            int n = rc[c], st = rstart[c];
            for (int j = lane; j < n; j += 64) {
                int pl = slots_lin[st + j];
                int r = (int)(((unsigned)pl) >> 17) - rbase;
                if ((unsigned)r < HALF) {
                    int pos = atomicAdd(&cur[r], 1);
                    stage[pos] = pl & 0x1FFFF;
                }
            }
        }
        __syncthreads();
        // phase 4: gather; wave per node, 8 groups x 8 lanes, register accum
        const int g = lane >> 3, c8 = lane & 7;
        const int4* row = (const int4*)emb16;
        for (int r = wid; r < rows_here; r += 8) {
            const int end_ = cur[r];           // after scatter: segment end
            const int beg_ = end_ - counts[r];
            float acc[8] = {0.f, 0.f, 0.f, 0.f, 0.f, 0.f, 0.f, 0.f};
            int e = beg_ + g;
            for (; e + 8 < end_; e += 16) {
                int s0 = stage[e];
                int s1 = stage[e + 8];
                int4 u0 = row[s0 * 8 + c8];
                int4 u1 = row[s1 * 8 + c8];
                acc[0] += __uint_as_float((unsigned)u0.x << 16) + __uint_as_float((unsigned)u1.x << 16);
                acc[1] += __uint_as_float(u0.x & 0xFFFF0000u)   + __uint_as_float(u1.x & 0xFFFF0000u);
                acc[2] += __uint_as_float((unsigned)u0.y << 16) + __uint_as_float((unsigned)u1.y << 16);
                acc[3] += __uint_as_float(u0.y & 0xFFFF0000u)   + __uint_as_float(u1.y & 0xFFFF0000u);
                acc[4] += __uint_as_float((unsigned)u0.z << 16) + __uint_as_float((unsigned)u1.z << 16);
                acc[5] += __uint_as_float(u0.z & 0xFFFF0000u)   + __uint_as_float(u1.z & 0xFFFF0000u);
                acc[6] += __uint_as_float((unsigned)u0.w << 16) + __uint_as_float((unsigned)u1.w << 16);
                acc[7] += __uint_as_float(u0.w & 0xFFFF0000u)   + __uint_as_float(u1.w & 0xFFFF0000u);
            }
            if (e < end_) {
                int s0 = stage[e];
                int4 u0 = row[s0 * 8 + c8];
                acc[0] += __uint_as_float((unsigned)u0.x << 16);
                acc[1] += __uint_as_float(u0.x & 0xFFFF0000u);
                acc[2] += __uint_as_float((unsigned)u0.y << 16);
                acc[3] += __uint_as_float(u0.y & 0xFFFF0000u);
                acc[4] += __uint_as_float((unsigned)u0.z << 16);
                acc[5] += __uint_as_float(u0.z & 0xFFFF0000u);
                acc[6] += __uint_as_float((unsigned)u0.w << 16);
                acc[7] += __uint_as_float(u0.w & 0xFFFF0000u);
            }
            #pragma unroll
            for (int off = 8; off <= 32; off <<= 1) {
                #pragma unroll
                for (int k = 0; k < 8; k++) acc[k] += __shfl_xor(acc[k], off, 64);
            }
            if (g == 0) {
                f32x4* out4 = (f32x4*)out;
                f32x4 o0 = {acc[0], acc[1], acc[2], acc[3]};
                f32x4 o1 = {acc[4], acc[5], acc[6], acc[7]};
                __builtin_nontemporal_store(o0, out4 + (size_t)(lo + r) * D4 + c8 * 2);
                __builtin_nontemporal_store(o1, out4 + (size_t)(lo + r) * D4 + c8 * 2 + 1);
            }
        }
    } else {
        // fallback (extreme skew): zero our rows (exclusively owned), atomic adds
        float4 z = make_float4(0.f, 0.f, 0.f, 0.f);
        float4* ob = (float4*)(out + (size_t)lo * D);
        for (int i = tid; i < rows_here * D4; i += 512) ob[i] = z;
        __syncthreads();
        for (int c = wid; c < NCH; c += 8) {
            int n = rc[c], st = rstart[c];
            for (int j = lane; j < n; j += 64) {
                int pl = slots_lin[st + j];
                int r = (int)(((unsigned)pl) >> 17) - rbase;
                if ((unsigned)r < HALF) {
                    int srcid = pl & 0x1FFFF;
                    float* orow = out + (size_t)(lo + r) * D;
                    const unsigned* rp = emb16 + (size_t)srcid * 32;
                    for (int k = 0; k < 32; k++) {
                        unsigned u = rp[k];
                        unsafeAtomicAdd(orow + 2 * k,     __uint_as_float(u << 16));
                        unsafeAtomicAdd(orow + 2 * k + 1, __uint_as_float(u & 0xFFFF0000u));
                    }
                }
            }
        }
    }
}

// ---------- Fallback: atomic scatter (ws too small / shape out of range) ------
__global__ void zero_out_kernel(float* __restrict__ out, int total4) {
    int i = blockIdx.x * blockDim.x + threadIdx.x;
    if (i < total4) ((float4*)out)[i] = make_float4(0.f, 0.f, 0.f, 0.f);
}

__global__ void scatter_fused_kernel(const float* __restrict__ x,
                                     const float* __restrict__ w,
                                     const int* __restrict__ src,
                                     const int* __restrict__ dst,
                                     float* __restrict__ out, int n_edges) {
    int t = blockIdx.x * blockDim.x + threadIdx.x;
    int e = t >> 4;
    int c = t & 15;
    if (e >= n_edges) return;
    int s = src[e];
    int d = dst[e];
    float4 xv = ((const float4*)x)[s * D4 + c];
    float4 wv = ((const float4*)w)[c];
    float* o = out + d * D + c * 4;
    unsafeAtomicAdd(o + 0, elu1(xv.x * wv.x));
    unsafeAtomicAdd(o + 1, elu1(xv.y * wv.y));
    unsafeAtomicAdd(o + 2, elu1(xv.z * wv.z));
    unsafeAtomicAdd(o + 3, elu1(xv.w * wv.w));
}

extern "C" void kernel_launch(void* const* d_in, const int* in_sizes, int n_in,
                              void* d_out, int out_size, void* d_ws, size_t ws_size,
                              hipStream_t stream) {
    const float* x   = (const float*)d_in[0];   // [N, 64] fp32
    const float* w   = (const float*)d_in[1];   // [1, 64] fp32
    const int*   src = (const int*)d_in[2];     // [E] int32
    const int*   dst = (const int*)d_in[3];     // [E] int32
    float* out = (float*)d_out;

    const int n_nodes = in_sizes[0] / D;
    const int n_edges = in_sizes[2];
    const int total4  = n_nodes * D4;
    const int total8  = n_nodes * 8;
    const int block = 256;

    const int NSB = (n_nodes + SBROWS - 1) >> SBSHIFT;
    const int NCH = (n_edges + CHUNK_E - 1) / CHUNK_E;

    auto align16 = [](size_t v) { return (v + 15) & ~size_t(15); };
    const size_t emb_b   = align16((size_t)n_nodes * D * 2);     // bf16
    const size_t slots_b = align16((size_t)NCH * CHUNK_E * 4);
    const size_t cbase_b = align16((size_t)NCH * 257 * 4);
    const size_t need = emb_b + slots_b + cbase_b;

    if (ws_size >= need && n_nodes <= 131072 && NSB <= NSB_MAX && NCH <= NCH_MAX) {
        char* p = (char*)d_ws;
        unsigned int* emb16 = (unsigned int*)p;  p += emb_b;
        int* slots_lin = (int*)p;  p += slots_b;
        int* cbase     = (int*)p;

        emb_kernel<<<(total8 + block - 1) / block, block, 0, stream>>>(
            x, w, (uint4*)emb16, total8);
        chunk_sort_kernel<<<NCH, 512, 0, stream>>>(
            src, dst, slots_lin, cbase, n_edges);
        sb_gather_kernel<<<2 * NSB, 512, 0, stream>>>(
            emb16, slots_lin, cbase, out, n_nodes, NCH);
    } else {
        zero_out_kernel<<<(total4 + block - 1) / block, block, 0, stream>>>(out, total4);
        const int nt = n_edges * 16;
        scatter_fused_kernel<<<(nt + block - 1) / block, block, 0, stream>>>(
            x, w, src, dst, out, n_edges);
    }
}